// Round 1
// baseline (248.265 us; speedup 1.0000x reference)
//
#include <hip/hip_runtime.h>
#include <hip/hip_bf16.h>
#include <math.h>

// ---------------- types / helpers ----------------
typedef __attribute__((ext_vector_type(8))) short short8;   // 8 x bf16 (4 VGPR)
typedef __attribute__((ext_vector_type(4))) float f32x4;

#define DMODEL 768
#define THREE_D 2304
#define FFDIM 3072
#define NSEQ 1024
#define NHEAD 12
#define HEADD 64
#define MROWS 4096   // B*N = 4*1024

__device__ __forceinline__ ushort f2bf(float f) {
  union { float f; unsigned u; } c; c.f = f;
  unsigned u = c.u;
  unsigned r = (u + 0x7fffu + ((u >> 16) & 1u)) >> 16;   // RNE
  return (ushort)r;
}

// ---------------- LayerNorm: fp32 in -> bf16 out ----------------
__global__ __launch_bounds__(256) void ln_kernel(const float* __restrict__ x,
    const float* __restrict__ g, const float* __restrict__ be,
    ushort* __restrict__ out) {
  int row = blockIdx.x;
  const float* xr = x + (size_t)row * DMODEL;
  int tid = threadIdx.x;
  float v0 = xr[tid], v1 = xr[tid + 256], v2 = xr[tid + 512];
  __shared__ float red1[4], red2[4];
  float s = v0 + v1 + v2;
  #pragma unroll
  for (int off = 32; off; off >>= 1) s += __shfl_xor(s, off);
  if ((tid & 63) == 0) red1[tid >> 6] = s;
  __syncthreads();
  float mean = (red1[0] + red1[1] + red1[2] + red1[3]) * (1.0f / 768.0f);
  float d0 = v0 - mean, d1 = v1 - mean, d2 = v2 - mean;
  float q = d0 * d0 + d1 * d1 + d2 * d2;
  #pragma unroll
  for (int off = 32; off; off >>= 1) q += __shfl_xor(q, off);
  if ((tid & 63) == 0) red2[tid >> 6] = q;
  __syncthreads();
  float var = (red2[0] + red2[1] + red2[2] + red2[3]) * (1.0f / 768.0f);
  float rs = rsqrtf(var + 1e-5f);
  size_t base = (size_t)row * DMODEL;
  out[base + tid]       = f2bf(d0 * rs * g[tid]       + be[tid]);
  out[base + tid + 256] = f2bf(d1 * rs * g[tid + 256] + be[tid + 256]);
  out[base + tid + 512] = f2bf(d2 * rs * g[tid + 512] + be[tid + 512]);
}

// ---------------- weight transpose-convert: W[K][N] f32 -> Wt[N][K] bf16 ----
__global__ void wt_kernel(const float* __restrict__ W, ushort* __restrict__ Wt,
                          int K, int N) {
  __shared__ float t[32][33];
  int n0 = blockIdx.x * 32, k0 = blockIdx.y * 32;
  int tx = threadIdx.x, ty = threadIdx.y;
  #pragma unroll
  for (int r = 0; r < 4; r++)
    t[ty + r * 8][tx] = W[(size_t)(k0 + ty + r * 8) * N + n0 + tx];
  __syncthreads();
  #pragma unroll
  for (int r = 0; r < 4; r++)
    Wt[(size_t)(n0 + ty + r * 8) * K + k0 + tx] = f2bf(t[tx][ty + r * 8]);
}

// ---------------- V transpose: qkv(V part) -> Vt[b][h][d][n] bf16 ----------
__global__ void vt_kernel(const ushort* __restrict__ qkv, ushort* __restrict__ Vt) {
  __shared__ ushort t[32][33];
  int n0 = blockIdx.x * 32, d0 = blockIdx.y * 32, bh = blockIdx.z;
  int b = bh / NHEAD, hh = bh % NHEAD;
  int tx = threadIdx.x, ty = threadIdx.y;
  #pragma unroll
  for (int r = 0; r < 4; r++)
    t[ty + r * 8][tx] = qkv[(size_t)(b * NSEQ + n0 + ty + r * 8) * THREE_D +
                            2 * DMODEL + hh * HEADD + d0 + tx];
  __syncthreads();
  #pragma unroll
  for (int r = 0; r < 4; r++)
    Vt[((size_t)bh * HEADD + d0 + ty + r * 8) * NSEQ + n0 + tx] = t[tx][ty + r * 8];
}

// ---------------- GEMM: C[M][N] = A[M][K](bf16) @ Wt[N][K]^T(bf16) + bias ---
// MODE 0: out bf16 = acc + bias
// MODE 1: out f32  = acc + bias + resid
// MODE 2: out bf16 = gelu_exact(acc + bias)
template <int MODE>
__global__ __launch_bounds__(256) void gemm_kernel(
    const ushort* __restrict__ A, const ushort* __restrict__ Bt,
    const float* __restrict__ bias, const float* __restrict__ resid,
    void* __restrict__ Cout, int Mtot, int Ntot, int K) {
  __shared__ ushort Alds[128][72];   // +8 pad: row stride 144B -> 2-way (free)
  __shared__ ushort Blds[128][72];
  int tid = threadIdx.x;
  int lane = tid & 63, wave = tid >> 6;
  int wm = wave >> 1, wn = wave & 1;        // 2x2 waves, 64x64 each
  int m0 = blockIdx.y * 128, n0 = blockIdx.x * 128;
  f32x4 acc[4][4] = {};
  for (int k0 = 0; k0 < K; k0 += 64) {
    #pragma unroll
    for (int i = 0; i < 4; i++) {            // 1024 chunks of 8 elems
      int c = tid + i * 256;
      int r = c >> 3, kk = (c & 7) * 8;      // lanes 0-7 = one 128B row
      *(int4*)&Alds[r][kk] = *(const int4*)&A[(size_t)(m0 + r) * K + k0 + kk];
      *(int4*)&Blds[r][kk] = *(const int4*)&Bt[(size_t)(n0 + r) * K + k0 + kk];
    }
    __syncthreads();
    #pragma unroll
    for (int ks = 0; ks < 2; ks++) {
      short8 af[4], bfr[4];
      int rsel = lane & 15, ko = ks * 32 + (lane >> 4) * 8;
      #pragma unroll
      for (int mi = 0; mi < 4; mi++)
        af[mi] = *(const short8*)&Alds[wm * 64 + mi * 16 + rsel][ko];
      #pragma unroll
      for (int ni = 0; ni < 4; ni++)
        bfr[ni] = *(const short8*)&Blds[wn * 64 + ni * 16 + rsel][ko];
      #pragma unroll
      for (int mi = 0; mi < 4; mi++)
        #pragma unroll
        for (int ni = 0; ni < 4; ni++)
          acc[mi][ni] = __builtin_amdgcn_mfma_f32_16x16x32_bf16(
              af[mi], bfr[ni], acc[mi][ni], 0, 0, 0);
    }
    __syncthreads();
  }
  // epilogue: C row = (lane>>4)*4+j within 16, col = lane&15
  int rbase = m0 + wm * 64, cbase = n0 + wn * 64;
  #pragma unroll
  for (int ni = 0; ni < 4; ni++) {
    int col = cbase + ni * 16 + (lane & 15);
    float bv = bias[col];
    #pragma unroll
    for (int mi = 0; mi < 4; mi++) {
      int row0 = rbase + mi * 16 + (lane >> 4) * 4;
      #pragma unroll
      for (int j = 0; j < 4; j++) {
        float v = acc[mi][ni][j] + bv;
        size_t idx = (size_t)(row0 + j) * Ntot + col;
        if (MODE == 0) {
          ((ushort*)Cout)[idx] = f2bf(v);
        } else if (MODE == 1) {
          ((float*)Cout)[idx] = v + resid[idx];
        } else {
          float gv = 0.5f * v * (1.0f + erff(v * 0.70710678118654752f));
          ((ushort*)Cout)[idx] = f2bf(gv);
        }
      }
    }
  }
}

// ---------------- flash attention ----------------
// grid: (16 qtiles, 48 b*h), 256 thr = 4 waves x 16 q-rows, KV tiles of 64
__global__ __launch_bounds__(256) void attn_kernel(
    const ushort* __restrict__ qkv, const ushort* __restrict__ Vt,
    ushort* __restrict__ o) {
  __shared__ ushort Klds[64][72];
  __shared__ ushort Vlds[64][72];
  __shared__ ushort Plds[4][16][72];
  int tid = threadIdx.x, lane = tid & 63, wave = tid >> 6;
  int qt = blockIdx.x, bh = blockIdx.y;
  int b = bh / NHEAD, hh = bh % NHEAD;
  int q0 = qt * 64;
  // Q fragments (hoisted): rows q0+wave*16+(lane&15), d = ks*32+(lane>>4)*8
  short8 qf[2];
  {
    int qrow = q0 + wave * 16 + (lane & 15);
    const ushort* qp = qkv + (size_t)(b * NSEQ + qrow) * THREE_D + hh * HEADD +
                       (lane >> 4) * 8;
    qf[0] = *(const short8*)qp;
    qf[1] = *(const short8*)(qp + 32);
  }
  f32x4 oacc[4] = {};
  float mrow[4], lrow[4];
  #pragma unroll
  for (int i = 0; i < 4; i++) { mrow[i] = -INFINITY; lrow[i] = 0.0f; }

  for (int kv0 = 0; kv0 < NSEQ; kv0 += 64) {
    #pragma unroll
    for (int i = 0; i < 2; i++) {           // stage K tile + Vt tile
      int c = tid + i * 256;
      int r = c >> 3, dd = (c & 7) * 8;
      *(int4*)&Klds[r][dd] = *(const int4*)&qkv[(size_t)(b * NSEQ + kv0 + r) * THREE_D +
                                                DMODEL + hh * HEADD + dd];
      *(int4*)&Vlds[r][dd] = *(const int4*)&Vt[((size_t)bh * HEADD + r) * NSEQ + kv0 + dd];
    }
    __syncthreads();
    // S = Q K^T  (16q x 64keys per wave)
    f32x4 sfr[4] = {};
    int rsel = lane & 15;
    #pragma unroll
    for (int ks = 0; ks < 2; ks++) {
      int ko = ks * 32 + (lane >> 4) * 8;
      #pragma unroll
      for (int nt = 0; nt < 4; nt++) {
        short8 kf = *(const short8*)&Klds[nt * 16 + rsel][ko];
        sfr[nt] = __builtin_amdgcn_mfma_f32_16x16x32_bf16(qf[ks], kf, sfr[nt], 0, 0, 0);
      }
    }
    #pragma unroll
    for (int nt = 0; nt < 4; nt++) sfr[nt] *= 0.125f;   // HD^-0.5
    // online softmax, wave-parallel (16-lane groups hold 16 cols of 4 rows)
    #pragma unroll
    for (int i = 0; i < 4; i++) {
      float mx = fmaxf(fmaxf(sfr[0][i], sfr[1][i]), fmaxf(sfr[2][i], sfr[3][i]));
      #pragma unroll
      for (int off = 1; off < 16; off <<= 1) mx = fmaxf(mx, __shfl_xor(mx, off));
      float mnew = fmaxf(mrow[i], mx);
      float alpha = __expf(mrow[i] - mnew);
      float psum = 0.0f;
      #pragma unroll
      for (int nt = 0; nt < 4; nt++) {
        float p = __expf(sfr[nt][i] - mnew);
        psum += p;
        Plds[wave][(lane >> 4) * 4 + i][nt * 16 + (lane & 15)] = f2bf(p);
      }
      #pragma unroll
      for (int off = 1; off < 16; off <<= 1) psum += __shfl_xor(psum, off);
      lrow[i] = lrow[i] * alpha + psum;
      mrow[i] = mnew;
      #pragma unroll
      for (int nt = 0; nt < 4; nt++) oacc[nt][i] *= alpha;
    }
    // O += P @ V
    #pragma unroll
    for (int ks = 0; ks < 2; ks++) {
      int ko = ks * 32 + (lane >> 4) * 8;
      short8 pf = *(const short8*)&Plds[wave][lane & 15][ko];
      #pragma unroll
      for (int nt = 0; nt < 4; nt++) {
        short8 vf = *(const short8*)&Vlds[nt * 16 + (lane & 15)][ko];
        oacc[nt] = __builtin_amdgcn_mfma_f32_16x16x32_bf16(pf, vf, oacc[nt], 0, 0, 0);
      }
    }
    __syncthreads();
  }
  // epilogue -> o[b][n][h*64+d] bf16
  #pragma unroll
  for (int nt = 0; nt < 4; nt++)
    #pragma unroll
    for (int i = 0; i < 4; i++) {
      int qrow = q0 + wave * 16 + (lane >> 4) * 4 + i;
      int col = hh * HEADD + nt * 16 + (lane & 15);
      o[(size_t)(b * NSEQ + qrow) * DMODEL + col] = f2bf(oacc[nt][i] / lrow[i]);
    }
}

// ---------------- launch ----------------
extern "C" void kernel_launch(void* const* d_in, const int* in_sizes, int n_in,
                              void* d_out, int out_size, void* d_ws, size_t ws_size,
                              hipStream_t stream) {
  const float* x      = (const float*)d_in[0];
  const float* w_qkv  = (const float*)d_in[1];
  const float* b_qkv  = (const float*)d_in[2];
  const float* w_proj = (const float*)d_in[3];
  const float* b_proj = (const float*)d_in[4];
  const float* w1     = (const float*)d_in[5];
  const float* b1     = (const float*)d_in[6];
  const float* w2     = (const float*)d_in[7];
  const float* b2     = (const float*)d_in[8];
  const float* g1     = (const float*)d_in[9];
  const float* be1    = (const float*)d_in[10];
  const float* g2     = (const float*)d_in[11];
  const float* be2    = (const float*)d_in[12];
  float* out = (float*)d_out;

  char* ws = (char*)d_ws;
  ushort* Wqkv_t  = (ushort*)(ws + 0);           // 2304*768*2  = 3538944
  ushort* Wproj_t = (ushort*)(ws + 3538944);     // 768*768*2   = 1179648
  ushort* W1_t    = (ushort*)(ws + 4718592);     // 3072*768*2  = 4718592
  ushort* W2_t    = (ushort*)(ws + 9437184);     // 768*3072*2  = 4718592
  ushort* hbuf    = (ushort*)(ws + 14155776);    // 4096*768*2  = 6291456 (h, then h2)
  ushort* qkv     = (ushort*)(ws + 20447232);    // max(qkv 18.9MB, ff1 25.2MB)
  ushort* ff1     = qkv;
  ushort* VtB     = (ushort*)(ws + 45613056);    // 4096*768*2
  ushort* obuf    = (ushort*)(ws + 51904512);    // 4096*768*2
  float*  x2      = (float*)(ws + 58195968);     // 4096*768*4 -> end 70778880

  dim3 tb(32, 8);
  wt_kernel<<<dim3(THREE_D / 32, DMODEL / 32), tb, 0, stream>>>(w_qkv, Wqkv_t, DMODEL, THREE_D);
  wt_kernel<<<dim3(DMODEL / 32, DMODEL / 32), tb, 0, stream>>>(w_proj, Wproj_t, DMODEL, DMODEL);
  wt_kernel<<<dim3(FFDIM / 32, DMODEL / 32), tb, 0, stream>>>(w1, W1_t, DMODEL, FFDIM);
  wt_kernel<<<dim3(DMODEL / 32, FFDIM / 32), tb, 0, stream>>>(w2, W2_t, FFDIM, DMODEL);

  ln_kernel<<<MROWS, 256, 0, stream>>>(x, g1, be1, hbuf);

  gemm_kernel<0><<<dim3(THREE_D / 128, MROWS / 128), 256, 0, stream>>>(
      hbuf, Wqkv_t, b_qkv, nullptr, qkv, MROWS, THREE_D, DMODEL);

  vt_kernel<<<dim3(NSEQ / 32, HEADD / 32, 4 * NHEAD), tb, 0, stream>>>(qkv, VtB);

  attn_kernel<<<dim3(NSEQ / 64, 4 * NHEAD), 256, 0, stream>>>(qkv, VtB, obuf);

  gemm_kernel<1><<<dim3(DMODEL / 128, MROWS / 128), 256, 0, stream>>>(
      obuf, Wproj_t, b_proj, x, x2, MROWS, DMODEL, DMODEL);

  ln_kernel<<<MROWS, 256, 0, stream>>>(x2, g2, be2, hbuf);

  gemm_kernel<2><<<dim3(FFDIM / 128, MROWS / 128), 256, 0, stream>>>(
      hbuf, W1_t, b1, nullptr, ff1, MROWS, FFDIM, DMODEL);

  gemm_kernel<1><<<dim3(DMODEL / 128, MROWS / 128), 256, 0, stream>>>(
      ff1, W2_t, b2, x2, out, MROWS, DMODEL, FFDIM);

  (void)in_sizes; (void)n_in; (void)out_size; (void)ws_size;
}

// Round 2
// 217.307 us; speedup vs baseline: 1.1425x; 1.1425x over previous
//
#include <hip/hip_runtime.h>
#include <hip/hip_bf16.h>
#include <math.h>

// ---------------- types / helpers ----------------
typedef __attribute__((ext_vector_type(8))) short short8;   // 8 x bf16 (4 VGPR)
typedef __attribute__((ext_vector_type(4))) float f32x4;

#define DMODEL 768
#define THREE_D 2304
#define FFDIM 3072
#define NSEQ 1024
#define NHEAD 12
#define HEADD 64
#define MROWS 4096   // B*N = 4*1024

__device__ __forceinline__ ushort f2bf(float f) {
  union { float f; unsigned u; } c; c.f = f;
  unsigned u = c.u;
  unsigned r = (u + 0x7fffu + ((u >> 16) & 1u)) >> 16;   // RNE
  return (ushort)r;
}

// async global->LDS, 16B per lane. LDS dest must be wave-uniform base;
// lane l lands at base + l*16.
__device__ __forceinline__ void load_lds16(const ushort* g, const ushort* l) {
  __builtin_amdgcn_global_load_lds(
      (const __attribute__((address_space(1))) unsigned int*)g,
      (__attribute__((address_space(3))) unsigned int*)l, 16, 0, 0);
}

// ---------------- LayerNorm: fp32 in -> bf16 out ----------------
__global__ __launch_bounds__(256) void ln_kernel(const float* __restrict__ x,
    const float* __restrict__ g, const float* __restrict__ be,
    ushort* __restrict__ out) {
  int row = blockIdx.x;
  const float* xr = x + (size_t)row * DMODEL;
  int tid = threadIdx.x;
  float v0 = xr[tid], v1 = xr[tid + 256], v2 = xr[tid + 512];
  __shared__ float red1[4], red2[4];
  float s = v0 + v1 + v2;
  #pragma unroll
  for (int off = 32; off; off >>= 1) s += __shfl_xor(s, off);
  if ((tid & 63) == 0) red1[tid >> 6] = s;
  __syncthreads();
  float mean = (red1[0] + red1[1] + red1[2] + red1[3]) * (1.0f / 768.0f);
  float d0 = v0 - mean, d1 = v1 - mean, d2 = v2 - mean;
  float q = d0 * d0 + d1 * d1 + d2 * d2;
  #pragma unroll
  for (int off = 32; off; off >>= 1) q += __shfl_xor(q, off);
  if ((tid & 63) == 0) red2[tid >> 6] = q;
  __syncthreads();
  float var = (red2[0] + red2[1] + red2[2] + red2[3]) * (1.0f / 768.0f);
  float rs = rsqrtf(var + 1e-5f);
  size_t base = (size_t)row * DMODEL;
  out[base + tid]       = f2bf(d0 * rs * g[tid]       + be[tid]);
  out[base + tid + 256] = f2bf(d1 * rs * g[tid + 256] + be[tid + 256]);
  out[base + tid + 512] = f2bf(d2 * rs * g[tid + 512] + be[tid + 512]);
}

// ---------------- weight transpose-convert: W[K][N] f32 -> Wt[N][K] bf16 ----
__global__ void wt_kernel(const float* __restrict__ W, ushort* __restrict__ Wt,
                          int K, int N) {
  __shared__ float t[32][33];
  int n0 = blockIdx.x * 32, k0 = blockIdx.y * 32;
  int tx = threadIdx.x, ty = threadIdx.y;
  #pragma unroll
  for (int r = 0; r < 4; r++)
    t[ty + r * 8][tx] = W[(size_t)(k0 + ty + r * 8) * N + n0 + tx];
  __syncthreads();
  #pragma unroll
  for (int r = 0; r < 4; r++)
    Wt[(size_t)(n0 + ty + r * 8) * K + k0 + tx] = f2bf(t[tx][ty + r * 8]);
}

// ---------------- V transpose: qkv(V part) -> Vt[b][h][d][n] bf16 ----------
__global__ void vt_kernel(const ushort* __restrict__ qkv, ushort* __restrict__ Vt) {
  __shared__ ushort t[32][33];
  int n0 = blockIdx.x * 32, d0 = blockIdx.y * 32, bh = blockIdx.z;
  int b = bh / NHEAD, hh = bh % NHEAD;
  int tx = threadIdx.x, ty = threadIdx.y;
  #pragma unroll
  for (int r = 0; r < 4; r++)
    t[ty + r * 8][tx] = qkv[(size_t)(b * NSEQ + n0 + ty + r * 8) * THREE_D +
                            2 * DMODEL + hh * HEADD + d0 + tx];
  __syncthreads();
  #pragma unroll
  for (int r = 0; r < 4; r++)
    Vt[((size_t)bh * HEADD + d0 + ty + r * 8) * NSEQ + n0 + tx] = t[tx][ty + r * 8];
}

// ---------------- GEMM: C[M][N] = A[M][K](bf16) @ Wt[N][K]^T(bf16) + bias ---
// m97 structure: global_load_lds width-16 staging, linear LDS + both-sides
// XOR swizzle (pre-swizzled source col, swizzled fragment read col).
// MODE 0: out bf16 = acc + bias
// MODE 1: out f32  = acc + bias + resid
// MODE 2: out bf16 = gelu_exact(acc + bias)
template <int BM, int BN, int MODE>
__global__ __launch_bounds__(256) void gemm_kernel(
    const ushort* __restrict__ A, const ushort* __restrict__ Bt,
    const float* __restrict__ bias, const float* __restrict__ resid,
    void* __restrict__ Cout, int gx, int Ntot, int K) {
  __shared__ ushort Alds[BM][64];
  __shared__ ushort Blds[BN][64];
  constexpr int WM = BM / 2, WN = BN / 2;   // 2x2 waves
  constexpr int FM = WM / 16, FN = WN / 16;
  int tid = threadIdx.x, lane = tid & 63, wave = tid >> 6;
  int wm = wave >> 1, wn = wave & 1;
  // XCD-chunked swizzle (grid always divisible by 8)
  int nwg = gridDim.x;
  int o = blockIdx.x;
  int wg = (o & 7) * (nwg >> 3) + (o >> 3);
  int bx = wg % gx, by = wg / gx;
  int m0 = by * BM, n0 = bx * BN;
  f32x4 acc[FM][FN] = {};
  for (int k0 = 0; k0 < K; k0 += 64) {
    #pragma unroll
    for (int i = 0; i < BM / 32; i++) {     // A tile: BM*64 elems, 16B/lane
      int c0 = i * 256 + wave * 64;         // wave-uniform chunk base
      int c = c0 + lane, r = c >> 3;
      int kk = ((c ^ r) & 7) * 8;           // pre-swizzled source col
      load_lds16(&A[(size_t)(m0 + r) * K + k0 + kk], (const ushort*)Alds + c0 * 8);
    }
    #pragma unroll
    for (int i = 0; i < BN / 32; i++) {
      int c0 = i * 256 + wave * 64;
      int c = c0 + lane, r = c >> 3;
      int kk = ((c ^ r) & 7) * 8;
      load_lds16(&Bt[(size_t)(n0 + r) * K + k0 + kk], (const ushort*)Blds + c0 * 8);
    }
    __syncthreads();   // compiler emits vmcnt(0) drain here
    #pragma unroll
    for (int ks = 0; ks < 2; ks++) {
      short8 af[FM], bfr[FN];
      int ko = ks * 32 + (lane >> 4) * 8;
      #pragma unroll
      for (int mi = 0; mi < FM; mi++) {
        int R = wm * WM + mi * 16 + (lane & 15);
        af[mi] = *(const short8*)&Alds[R][ko ^ ((R & 7) * 8)];
      }
      #pragma unroll
      for (int ni = 0; ni < FN; ni++) {
        int R = wn * WN + ni * 16 + (lane & 15);
        bfr[ni] = *(const short8*)&Blds[R][ko ^ ((R & 7) * 8)];
      }
      #pragma unroll
      for (int mi = 0; mi < FM; mi++)
        #pragma unroll
        for (int ni = 0; ni < FN; ni++)
          acc[mi][ni] = __builtin_amdgcn_mfma_f32_16x16x32_bf16(
              af[mi], bfr[ni], acc[mi][ni], 0, 0, 0);
    }
    __syncthreads();
  }
  // epilogue: C row = (lane>>4)*4+j within 16, col = lane&15
  int rbase = m0 + wm * WM, cbase = n0 + wn * WN;
  #pragma unroll
  for (int ni = 0; ni < FN; ni++) {
    int col = cbase + ni * 16 + (lane & 15);
    float bv = bias[col];
    #pragma unroll
    for (int mi = 0; mi < FM; mi++) {
      int row0 = rbase + mi * 16 + (lane >> 4) * 4;
      #pragma unroll
      for (int j = 0; j < 4; j++) {
        float v = acc[mi][ni][j] + bv;
        size_t idx = (size_t)(row0 + j) * Ntot + col;
        if (MODE == 0) {
          ((ushort*)Cout)[idx] = f2bf(v);
        } else if (MODE == 1) {
          ((float*)Cout)[idx] = v + resid[idx];
        } else {
          float gv = 0.5f * v * (1.0f + erff(v * 0.70710678118654752f));
          ((ushort*)Cout)[idx] = f2bf(gv);
        }
      }
    }
  }
}

// ---------------- flash attention ----------------
// grid: (16 qtiles, 48 b*h), 256 thr = 4 waves x 16 q-rows, KV tiles of 64
__global__ __launch_bounds__(256) void attn_kernel(
    const ushort* __restrict__ qkv, const ushort* __restrict__ Vt,
    ushort* __restrict__ o) {
  __shared__ ushort Klds[64][72];
  __shared__ ushort Vlds[64][72];
  __shared__ ushort Plds[4][16][72];
  int tid = threadIdx.x, lane = tid & 63, wave = tid >> 6;
  int qt = blockIdx.x, bh = blockIdx.y;
  int b = bh / NHEAD, hh = bh % NHEAD;
  int q0 = qt * 64;
  short8 qf[2];
  {
    int qrow = q0 + wave * 16 + (lane & 15);
    const ushort* qp = qkv + (size_t)(b * NSEQ + qrow) * THREE_D + hh * HEADD +
                       (lane >> 4) * 8;
    qf[0] = *(const short8*)qp;
    qf[1] = *(const short8*)(qp + 32);
  }
  f32x4 oacc[4] = {};
  float mrow[4], lrow[4];
  #pragma unroll
  for (int i = 0; i < 4; i++) { mrow[i] = -INFINITY; lrow[i] = 0.0f; }

  for (int kv0 = 0; kv0 < NSEQ; kv0 += 64) {
    #pragma unroll
    for (int i = 0; i < 2; i++) {           // stage K tile + Vt tile
      int c = tid + i * 256;
      int r = c >> 3, dd = (c & 7) * 8;
      *(int4*)&Klds[r][dd] = *(const int4*)&qkv[(size_t)(b * NSEQ + kv0 + r) * THREE_D +
                                                DMODEL + hh * HEADD + dd];
      *(int4*)&Vlds[r][dd] = *(const int4*)&Vt[((size_t)bh * HEADD + r) * NSEQ + kv0 + dd];
    }
    __syncthreads();
    f32x4 sfr[4] = {};
    int rsel = lane & 15;
    #pragma unroll
    for (int ks = 0; ks < 2; ks++) {
      int ko = ks * 32 + (lane >> 4) * 8;
      #pragma unroll
      for (int nt = 0; nt < 4; nt++) {
        short8 kf = *(const short8*)&Klds[nt * 16 + rsel][ko];
        sfr[nt] = __builtin_amdgcn_mfma_f32_16x16x32_bf16(qf[ks], kf, sfr[nt], 0, 0, 0);
      }
    }
    #pragma unroll
    for (int nt = 0; nt < 4; nt++) sfr[nt] *= 0.125f;   // HD^-0.5
    #pragma unroll
    for (int i = 0; i < 4; i++) {
      float mx = fmaxf(fmaxf(sfr[0][i], sfr[1][i]), fmaxf(sfr[2][i], sfr[3][i]));
      #pragma unroll
      for (int off = 1; off < 16; off <<= 1) mx = fmaxf(mx, __shfl_xor(mx, off));
      float mnew = fmaxf(mrow[i], mx);
      float alpha = __expf(mrow[i] - mnew);
      float psum = 0.0f;
      #pragma unroll
      for (int nt = 0; nt < 4; nt++) {
        float p = __expf(sfr[nt][i] - mnew);
        psum += p;
        Plds[wave][(lane >> 4) * 4 + i][nt * 16 + (lane & 15)] = f2bf(p);
      }
      #pragma unroll
      for (int off = 1; off < 16; off <<= 1) psum += __shfl_xor(psum, off);
      lrow[i] = lrow[i] * alpha + psum;
      mrow[i] = mnew;
      #pragma unroll
      for (int nt = 0; nt < 4; nt++) oacc[nt][i] *= alpha;
    }
    #pragma unroll
    for (int ks = 0; ks < 2; ks++) {
      int ko = ks * 32 + (lane >> 4) * 8;
      short8 pf = *(const short8*)&Plds[wave][lane & 15][ko];
      #pragma unroll
      for (int nt = 0; nt < 4; nt++) {
        short8 vf = *(const short8*)&Vlds[nt * 16 + (lane & 15)][ko];
        oacc[nt] = __builtin_amdgcn_mfma_f32_16x16x32_bf16(pf, vf, oacc[nt], 0, 0, 0);
      }
    }
    __syncthreads();
  }
  #pragma unroll
  for (int nt = 0; nt < 4; nt++)
    #pragma unroll
    for (int i = 0; i < 4; i++) {
      int qrow = q0 + wave * 16 + (lane >> 4) * 4 + i;
      int col = hh * HEADD + nt * 16 + (lane & 15);
      o[(size_t)(b * NSEQ + qrow) * DMODEL + col] = f2bf(oacc[nt][i] / lrow[i]);
    }
}

// ---------------- launch ----------------
extern "C" void kernel_launch(void* const* d_in, const int* in_sizes, int n_in,
                              void* d_out, int out_size, void* d_ws, size_t ws_size,
                              hipStream_t stream) {
  const float* x      = (const float*)d_in[0];
  const float* w_qkv  = (const float*)d_in[1];
  const float* b_qkv  = (const float*)d_in[2];
  const float* w_proj = (const float*)d_in[3];
  const float* b_proj = (const float*)d_in[4];
  const float* w1     = (const float*)d_in[5];
  const float* b1     = (const float*)d_in[6];
  const float* w2     = (const float*)d_in[7];
  const float* b2     = (const float*)d_in[8];
  const float* g1     = (const float*)d_in[9];
  const float* be1    = (const float*)d_in[10];
  const float* g2     = (const float*)d_in[11];
  const float* be2    = (const float*)d_in[12];
  float* out = (float*)d_out;

  char* ws = (char*)d_ws;
  ushort* Wqkv_t  = (ushort*)(ws + 0);           // 2304*768*2  = 3538944
  ushort* Wproj_t = (ushort*)(ws + 3538944);     // 768*768*2   = 1179648
  ushort* W1_t    = (ushort*)(ws + 4718592);     // 3072*768*2  = 4718592
  ushort* W2_t    = (ushort*)(ws + 9437184);     // 768*3072*2  = 4718592
  ushort* hbuf    = (ushort*)(ws + 14155776);    // 4096*768*2  = 6291456 (h, then h2)
  ushort* qkv     = (ushort*)(ws + 20447232);    // max(qkv 18.9MB, ff1 25.2MB)
  ushort* ff1     = qkv;
  ushort* VtB     = (ushort*)(ws + 45613056);    // 4096*768*2
  ushort* obuf    = (ushort*)(ws + 51904512);    // 4096*768*2
  float*  x2      = (float*)(ws + 58195968);     // 4096*768*4 -> end 70778880

  dim3 tb(32, 8);
  wt_kernel<<<dim3(THREE_D / 32, DMODEL / 32), tb, 0, stream>>>(w_qkv, Wqkv_t, DMODEL, THREE_D);
  wt_kernel<<<dim3(DMODEL / 32, DMODEL / 32), tb, 0, stream>>>(w_proj, Wproj_t, DMODEL, DMODEL);
  wt_kernel<<<dim3(FFDIM / 32, DMODEL / 32), tb, 0, stream>>>(w1, W1_t, DMODEL, FFDIM);
  wt_kernel<<<dim3(DMODEL / 32, FFDIM / 32), tb, 0, stream>>>(w2, W2_t, FFDIM, DMODEL);

  ln_kernel<<<MROWS, 256, 0, stream>>>(x, g1, be1, hbuf);

  // QKV: M=4096 N=2304 K=768, 128x128 -> 18*32=576 blocks
  gemm_kernel<128, 128, 0><<<576, 256, 0, stream>>>(
      hbuf, Wqkv_t, b_qkv, nullptr, qkv, THREE_D / 128, THREE_D, DMODEL);

  vt_kernel<<<dim3(NSEQ / 32, HEADD / 32, 4 * NHEAD), tb, 0, stream>>>(qkv, VtB);

  attn_kernel<<<dim3(NSEQ / 64, 4 * NHEAD), 256, 0, stream>>>(qkv, VtB, obuf);

  // proj: M=4096 N=768 K=768, 128x64 -> 12*32=384 blocks
  gemm_kernel<128, 64, 1><<<384, 256, 0, stream>>>(
      obuf, Wproj_t, b_proj, x, x2, DMODEL / 64, DMODEL, DMODEL);

  ln_kernel<<<MROWS, 256, 0, stream>>>(x2, g2, be2, hbuf);

  // FF1: M=4096 N=3072 K=768, 128x128 -> 24*32=768 blocks
  gemm_kernel<128, 128, 2><<<768, 256, 0, stream>>>(
      hbuf, W1_t, b1, nullptr, ff1, FFDIM / 128, FFDIM, DMODEL);

  // FF2: M=4096 N=768 K=3072, 128x64 -> 384 blocks
  gemm_kernel<128, 64, 1><<<384, 256, 0, stream>>>(
      ff1, W2_t, b2, x2, out, DMODEL / 64, DMODEL, FFDIM);

  (void)in_sizes; (void)n_in; (void)out_size; (void)ws_size;
}

// Round 3
// 202.509 us; speedup vs baseline: 1.2259x; 1.0731x over previous
//
#include <hip/hip_runtime.h>
#include <hip/hip_bf16.h>
#include <math.h>

// ---------------- types / helpers ----------------
typedef __attribute__((ext_vector_type(8))) short short8;   // 8 x bf16 (4 VGPR)
typedef __attribute__((ext_vector_type(4))) float f32x4;

#define DMODEL 768
#define THREE_D 2304
#define FFDIM 3072
#define NSEQ 1024
#define NHEAD 12
#define HEADD 64
#define MROWS 4096   // B*N = 4*1024

__device__ __forceinline__ ushort f2bf(float f) {
  union { float f; unsigned u; } c; c.f = f;
  unsigned u = c.u;
  unsigned r = (u + 0x7fffu + ((u >> 16) & 1u)) >> 16;   // RNE
  return (ushort)r;
}

__device__ __forceinline__ unsigned pack2bf(float a, float b) {
  union { __hip_bfloat162 h; unsigned u; } c;
  c.h = __float22bfloat162_rn(make_float2(a, b));   // v_cvt_pk_bf16_f32
  return c.u;
}

// async global->LDS, 16B per lane. LDS dest must be wave-uniform base;
// lane l lands at base + l*16.
__device__ __forceinline__ void load_lds16(const ushort* g, const ushort* l) {
  __builtin_amdgcn_global_load_lds(
      (const __attribute__((address_space(1))) unsigned int*)g,
      (__attribute__((address_space(3))) unsigned int*)l, 16, 0, 0);
}

// ---------------- LayerNorm: fp32 in -> bf16 out ----------------
__global__ __launch_bounds__(256) void ln_kernel(const float* __restrict__ x,
    const float* __restrict__ g, const float* __restrict__ be,
    ushort* __restrict__ out) {
  int row = blockIdx.x;
  const float* xr = x + (size_t)row * DMODEL;
  int tid = threadIdx.x;
  float v0 = xr[tid], v1 = xr[tid + 256], v2 = xr[tid + 512];
  __shared__ float red1[4], red2[4];
  float s = v0 + v1 + v2;
  #pragma unroll
  for (int off = 32; off; off >>= 1) s += __shfl_xor(s, off);
  if ((tid & 63) == 0) red1[tid >> 6] = s;
  __syncthreads();
  float mean = (red1[0] + red1[1] + red1[2] + red1[3]) * (1.0f / 768.0f);
  float d0 = v0 - mean, d1 = v1 - mean, d2 = v2 - mean;
  float q = d0 * d0 + d1 * d1 + d2 * d2;
  #pragma unroll
  for (int off = 32; off; off >>= 1) q += __shfl_xor(q, off);
  if ((tid & 63) == 0) red2[tid >> 6] = q;
  __syncthreads();
  float var = (red2[0] + red2[1] + red2[2] + red2[3]) * (1.0f / 768.0f);
  float rs = rsqrtf(var + 1e-5f);
  size_t base = (size_t)row * DMODEL;
  out[base + tid]       = f2bf(d0 * rs * g[tid]       + be[tid]);
  out[base + tid + 256] = f2bf(d1 * rs * g[tid + 256] + be[tid + 256]);
  out[base + tid + 512] = f2bf(d2 * rs * g[tid + 512] + be[tid + 512]);
}

// ---------------- weight transpose-convert: W[K][N] f32 -> Wt[N][K] bf16 ----
__global__ void wt_kernel(const float* __restrict__ W, ushort* __restrict__ Wt,
                          int K, int N) {
  __shared__ float t[32][33];
  int n0 = blockIdx.x * 32, k0 = blockIdx.y * 32;
  int tx = threadIdx.x, ty = threadIdx.y;
  #pragma unroll
  for (int r = 0; r < 4; r++)
    t[ty + r * 8][tx] = W[(size_t)(k0 + ty + r * 8) * N + n0 + tx];
  __syncthreads();
  #pragma unroll
  for (int r = 0; r < 4; r++)
    Wt[(size_t)(n0 + ty + r * 8) * K + k0 + tx] = f2bf(t[tx][ty + r * 8]);
}

// ---------------- V transpose: qkv(V part) -> Vt[b][h][d][perm(n)] bf16 ----
// Key permutation within each 64-key tile: k' = (k&15)*4 + ((k>>4)&3).
// PV contracts over keys; P columns use the same permutation -> invariant.
__global__ void vt_kernel(const ushort* __restrict__ qkv, ushort* __restrict__ Vt) {
  __shared__ ushort t[32][33];
  int n0 = blockIdx.x * 32, d0 = blockIdx.y * 32, bh = blockIdx.z;
  int b = bh / NHEAD, hh = bh % NHEAD;
  int tx = threadIdx.x, ty = threadIdx.y;
  #pragma unroll
  for (int r = 0; r < 4; r++)
    t[ty + r * 8][tx] = qkv[(size_t)(b * NSEQ + n0 + ty + r * 8) * THREE_D +
                            2 * DMODEL + hh * HEADD + d0 + tx];
  __syncthreads();
  #pragma unroll
  for (int r = 0; r < 4; r++) {
    int n = n0 + tx;
    int np = (n & ~63) | (((n & 15) << 2) | ((n >> 4) & 3));
    Vt[((size_t)bh * HEADD + d0 + ty + r * 8) * NSEQ + np] = t[tx][ty + r * 8];
  }
}

// ---------------- GEMM: C[M][N] = A[M][K](bf16) @ Wt[N][K]^T(bf16) + bias ---
// m97 structure: global_load_lds width-16 staging, linear LDS + both-sides
// XOR swizzle (pre-swizzled source col, swizzled fragment read col).
// MODE 0: out bf16 = acc + bias
// MODE 1: out f32  = acc + bias + resid
// MODE 2: out bf16 = gelu_exact(acc + bias)
template <int BM, int BN, int MODE>
__global__ __launch_bounds__(256) void gemm_kernel(
    const ushort* __restrict__ A, const ushort* __restrict__ Bt,
    const float* __restrict__ bias, const float* __restrict__ resid,
    void* __restrict__ Cout, int gx, int Ntot, int K) {
  __shared__ ushort Alds[BM][64];
  __shared__ ushort Blds[BN][64];
  constexpr int WM = BM / 2, WN = BN / 2;   // 2x2 waves
  constexpr int FM = WM / 16, FN = WN / 16;
  int tid = threadIdx.x, lane = tid & 63, wave = tid >> 6;
  int wm = wave >> 1, wn = wave & 1;
  // XCD-chunked swizzle (grid always divisible by 8)
  int nwg = gridDim.x;
  int o = blockIdx.x;
  int wg = (o & 7) * (nwg >> 3) + (o >> 3);
  int bx = wg % gx, by = wg / gx;
  int m0 = by * BM, n0 = bx * BN;
  f32x4 acc[FM][FN] = {};
  for (int k0 = 0; k0 < K; k0 += 64) {
    #pragma unroll
    for (int i = 0; i < BM / 32; i++) {     // A tile: BM*64 elems, 16B/lane
      int c0 = i * 256 + wave * 64;         // wave-uniform chunk base
      int c = c0 + lane, r = c >> 3;
      int kk = ((c ^ r) & 7) * 8;           // pre-swizzled source col
      load_lds16(&A[(size_t)(m0 + r) * K + k0 + kk], (const ushort*)Alds + c0 * 8);
    }
    #pragma unroll
    for (int i = 0; i < BN / 32; i++) {
      int c0 = i * 256 + wave * 64;
      int c = c0 + lane, r = c >> 3;
      int kk = ((c ^ r) & 7) * 8;
      load_lds16(&Bt[(size_t)(n0 + r) * K + k0 + kk], (const ushort*)Blds + c0 * 8);
    }
    __syncthreads();   // compiler emits vmcnt(0) drain here
    #pragma unroll
    for (int ks = 0; ks < 2; ks++) {
      short8 af[FM], bfr[FN];
      int ko = ks * 32 + (lane >> 4) * 8;
      #pragma unroll
      for (int mi = 0; mi < FM; mi++) {
        int R = wm * WM + mi * 16 + (lane & 15);
        af[mi] = *(const short8*)&Alds[R][ko ^ ((R & 7) * 8)];
      }
      #pragma unroll
      for (int ni = 0; ni < FN; ni++) {
        int R = wn * WN + ni * 16 + (lane & 15);
        bfr[ni] = *(const short8*)&Blds[R][ko ^ ((R & 7) * 8)];
      }
      #pragma unroll
      for (int mi = 0; mi < FM; mi++)
        #pragma unroll
        for (int ni = 0; ni < FN; ni++)
          acc[mi][ni] = __builtin_amdgcn_mfma_f32_16x16x32_bf16(
              af[mi], bfr[ni], acc[mi][ni], 0, 0, 0);
    }
    __syncthreads();
  }
  // epilogue: C row = (lane>>4)*4+j within 16, col = lane&15
  int rbase = m0 + wm * WM, cbase = n0 + wn * WN;
  #pragma unroll
  for (int ni = 0; ni < FN; ni++) {
    int col = cbase + ni * 16 + (lane & 15);
    float bv = bias[col];
    #pragma unroll
    for (int mi = 0; mi < FM; mi++) {
      int row0 = rbase + mi * 16 + (lane >> 4) * 4;
      #pragma unroll
      for (int j = 0; j < 4; j++) {
        float v = acc[mi][ni][j] + bv;
        size_t idx = (size_t)(row0 + j) * Ntot + col;
        if (MODE == 0) {
          ((ushort*)Cout)[idx] = f2bf(v);
        } else if (MODE == 1) {
          ((float*)Cout)[idx] = v + resid[idx];
        } else {
          float gv = 0.5f * v * (1.0f + erff(v * 0.70710678118654752f));
          ((ushort*)Cout)[idx] = f2bf(gv);
        }
      }
    }
  }
}

// ---------------- flash attention ----------------
// grid: (16 qtiles, 48 b*h), 256 thr = 4 waves x 16 q-rows, KV tiles of 64.
// exp2-domain softmax, MFMA-ones row-sum, packed P writes (key-permuted V),
// double-buffered K/V with reg-staged issue-early/write-late, defer-max.
__global__ __launch_bounds__(256) void attn_kernel(
    const ushort* __restrict__ qkv, const ushort* __restrict__ Vt,
    ushort* __restrict__ o) {
  __shared__ ushort Klds[2][64][72];
  __shared__ ushort Vlds[2][64][72];
  __shared__ ushort Plds[4][16][72];
  const float CL2 = 0.18033688011112042f;   // 0.125 * log2(e)
  int tid = threadIdx.x, lane = tid & 63, wave = tid >> 6;
  int qt = blockIdx.x, bh = blockIdx.y;
  int b = bh / NHEAD, hh = bh % NHEAD;
  int q0 = qt * 64;
  int rsel = lane & 15, quad = lane >> 4;

  short8 qf[2];
  {
    int qrow = q0 + wave * 16 + rsel;
    const ushort* qp = qkv + (size_t)(b * NSEQ + qrow) * THREE_D + hh * HEADD + quad * 8;
    qf[0] = *(const short8*)qp;
    qf[1] = *(const short8*)(qp + 32);
  }
  short8 onesf;
  #pragma unroll
  for (int i = 0; i < 8; i++) onesf[i] = (short)0x3F80;   // bf16 1.0

  // staging geometry: 512 chunks of 8 elems over 2 per-lane loads
  int r0 = tid >> 3, d0 = (tid & 7) * 8;
  int c1 = tid + 256, r1 = c1 >> 3, d1 = (c1 & 7) * 8;
  const ushort* Kg = qkv + (size_t)b * NSEQ * THREE_D + DMODEL + hh * HEADD;
  const ushort* Vg = Vt + (size_t)bh * HEADD * NSEQ;
  int4 kr0, kr1, vr0, vr1;
  auto LD = [&](int kv0) {
    kr0 = *(const int4*)&Kg[(size_t)(kv0 + r0) * THREE_D + d0];
    kr1 = *(const int4*)&Kg[(size_t)(kv0 + r1) * THREE_D + d1];
    vr0 = *(const int4*)&Vg[(size_t)r0 * NSEQ + kv0 + d0];
    vr1 = *(const int4*)&Vg[(size_t)r1 * NSEQ + kv0 + d1];
  };
  auto ST = [&](int bf) {
    *(int4*)&Klds[bf][r0][d0] = kr0;
    *(int4*)&Klds[bf][r1][d1] = kr1;
    *(int4*)&Vlds[bf][r0][d0] = vr0;
    *(int4*)&Vlds[bf][r1][d1] = vr1;
  };

  f32x4 oacc[4] = {};
  f32x4 osum = {};
  float m2[4];
  #pragma unroll
  for (int i = 0; i < 4; i++) m2[i] = -INFINITY;

  LD(0); ST(0); __syncthreads();

  for (int t = 0; t < 16; t++) {
    int bf = t & 1;
    if (t < 15) LD((t + 1) * 64);           // issue next-tile loads early
    // ---- S = Q K^T (raw, scale folded into exp2 constant) ----
    f32x4 sfr[4] = {};
    __builtin_amdgcn_s_setprio(1);
    #pragma unroll
    for (int ks = 0; ks < 2; ks++) {
      int ko = ks * 32 + quad * 8;
      #pragma unroll
      for (int nt = 0; nt < 4; nt++) {
        short8 kf = *(const short8*)&Klds[bf][nt * 16 + rsel][ko];
        sfr[nt] = __builtin_amdgcn_mfma_f32_16x16x32_bf16(qf[ks], kf, sfr[nt], 0, 0, 0);
      }
    }
    __builtin_amdgcn_s_setprio(0);
    // ---- online softmax (exp2 domain) ----
    float m2c[4];
    bool ok = true;
    #pragma unroll
    for (int i = 0; i < 4; i++) {
      float mx = fmaxf(fmaxf(sfr[0][i], sfr[1][i]), fmaxf(sfr[2][i], sfr[3][i]));
      #pragma unroll
      for (int off = 1; off < 16; off <<= 1) mx = fmaxf(mx, __shfl_xor(mx, off));
      m2c[i] = mx * CL2;
      ok = ok && (m2c[i] <= m2[i] + 8.0f);
    }
    if (!__all(ok)) {                        // rescale path
      #pragma unroll
      for (int i = 0; i < 4; i++) {
        float mn = fmaxf(m2[i], m2c[i]);
        float al = exp2f(m2[i] - mn);
        m2[i] = mn;
        #pragma unroll
        for (int nt = 0; nt < 4; nt++) oacc[nt][i] *= al;
        osum[i] *= al;
      }
    }
    #pragma unroll
    for (int i = 0; i < 4; i++) {
      float p0 = exp2f(fmaf(sfr[0][i], CL2, -m2[i]));
      float p1 = exp2f(fmaf(sfr[1][i], CL2, -m2[i]));
      float p2 = exp2f(fmaf(sfr[2][i], CL2, -m2[i]));
      float p3 = exp2f(fmaf(sfr[3][i], CL2, -m2[i]));
      // columns k' = rsel*4 + nt  (key-permuted; V uses same permutation)
      uint2 pw = make_uint2(pack2bf(p0, p1), pack2bf(p2, p3));
      *(uint2*)&Plds[wave][quad * 4 + i][rsel * 4] = pw;
    }
    // ---- O += P @ V ; row-sum via ones-column MFMA ----
    __builtin_amdgcn_s_setprio(1);
    #pragma unroll
    for (int ks = 0; ks < 2; ks++) {
      int ko = ks * 32 + quad * 8;
      short8 pf = *(const short8*)&Plds[wave][rsel][ko];
      #pragma unroll
      for (int nt = 0; nt < 4; nt++) {
        short8 vf = *(const short8*)&Vlds[bf][nt * 16 + rsel][ko];
        oacc[nt] = __builtin_amdgcn_mfma_f32_16x16x32_bf16(pf, vf, oacc[nt], 0, 0, 0);
      }
      osum = __builtin_amdgcn_mfma_f32_16x16x32_bf16(pf, onesf, osum, 0, 0, 0);
    }
    __builtin_amdgcn_s_setprio(0);
    if (t < 15) ST(bf ^ 1);                  // write-late into other buffer
    __syncthreads();
  }
  // ---- epilogue ----
  float rin[4];
  #pragma unroll
  for (int i = 0; i < 4; i++) rin[i] = __builtin_amdgcn_rcpf(osum[i]);
  #pragma unroll
  for (int nt = 0; nt < 4; nt++)
    #pragma unroll
    for (int i = 0; i < 4; i++) {
      int qrow = q0 + wave * 16 + quad * 4 + i;
      int col = hh * HEADD + nt * 16 + rsel;
      o[(size_t)(b * NSEQ + qrow) * DMODEL + col] = f2bf(oacc[nt][i] * rin[i]);
    }
}

// ---------------- launch ----------------
extern "C" void kernel_launch(void* const* d_in, const int* in_sizes, int n_in,
                              void* d_out, int out_size, void* d_ws, size_t ws_size,
                              hipStream_t stream) {
  const float* x      = (const float*)d_in[0];
  const float* w_qkv  = (const float*)d_in[1];
  const float* b_qkv  = (const float*)d_in[2];
  const float* w_proj = (const float*)d_in[3];
  const float* b_proj = (const float*)d_in[4];
  const float* w1     = (const float*)d_in[5];
  const float* b1     = (const float*)d_in[6];
  const float* w2     = (const float*)d_in[7];
  const float* b2     = (const float*)d_in[8];
  const float* g1     = (const float*)d_in[9];
  const float* be1    = (const float*)d_in[10];
  const float* g2     = (const float*)d_in[11];
  const float* be2    = (const float*)d_in[12];
  float* out = (float*)d_out;

  char* ws = (char*)d_ws;
  ushort* Wqkv_t  = (ushort*)(ws + 0);           // 2304*768*2  = 3538944
  ushort* Wproj_t = (ushort*)(ws + 3538944);     // 768*768*2   = 1179648
  ushort* W1_t    = (ushort*)(ws + 4718592);     // 3072*768*2  = 4718592
  ushort* W2_t    = (ushort*)(ws + 9437184);     // 768*3072*2  = 4718592
  ushort* hbuf    = (ushort*)(ws + 14155776);    // 4096*768*2  = 6291456 (h, then h2)
  ushort* qkv     = (ushort*)(ws + 20447232);    // max(qkv 18.9MB, ff1 25.2MB)
  ushort* ff1     = qkv;
  ushort* VtB     = (ushort*)(ws + 45613056);    // 4096*768*2
  ushort* obuf    = (ushort*)(ws + 51904512);    // 4096*768*2
  float*  x2      = (float*)(ws + 58195968);     // 4096*768*4 -> end 70778880

  dim3 tb(32, 8);
  wt_kernel<<<dim3(THREE_D / 32, DMODEL / 32), tb, 0, stream>>>(w_qkv, Wqkv_t, DMODEL, THREE_D);
  wt_kernel<<<dim3(DMODEL / 32, DMODEL / 32), tb, 0, stream>>>(w_proj, Wproj_t, DMODEL, DMODEL);
  wt_kernel<<<dim3(FFDIM / 32, DMODEL / 32), tb, 0, stream>>>(w1, W1_t, DMODEL, FFDIM);
  wt_kernel<<<dim3(DMODEL / 32, FFDIM / 32), tb, 0, stream>>>(w2, W2_t, FFDIM, DMODEL);

  ln_kernel<<<MROWS, 256, 0, stream>>>(x, g1, be1, hbuf);

  // QKV: M=4096 N=2304 K=768, 128x128 -> 18*32=576 blocks
  gemm_kernel<128, 128, 0><<<576, 256, 0, stream>>>(
      hbuf, Wqkv_t, b_qkv, nullptr, qkv, THREE_D / 128, THREE_D, DMODEL);

  vt_kernel<<<dim3(NSEQ / 32, HEADD / 32, 4 * NHEAD), tb, 0, stream>>>(qkv, VtB);

  attn_kernel<<<dim3(NSEQ / 64, 4 * NHEAD), 256, 0, stream>>>(qkv, VtB, obuf);

  // proj: M=4096 N=768 K=768, 128x64 -> 12*32=384 blocks
  gemm_kernel<128, 64, 1><<<384, 256, 0, stream>>>(
      obuf, Wproj_t, b_proj, x, x2, DMODEL / 64, DMODEL, DMODEL);

  ln_kernel<<<MROWS, 256, 0, stream>>>(x2, g2, be2, hbuf);

  // FF1: M=4096 N=3072 K=768, 128x128 -> 24*32=768 blocks
  gemm_kernel<128, 128, 2><<<768, 256, 0, stream>>>(
      hbuf, W1_t, b1, nullptr, ff1, FFDIM / 128, FFDIM, DMODEL);

  // FF2: M=4096 N=768 K=3072, 128x64 -> 384 blocks
  gemm_kernel<128, 64, 1><<<384, 256, 0, stream>>>(
      ff1, W2_t, b2, x2, out, DMODEL / 64, DMODEL, FFDIM);

  (void)in_sizes; (void)n_in; (void)out_size; (void)ws_size;
}

// Round 4
// 200.876 us; speedup vs baseline: 1.2359x; 1.0081x over previous
//
#include <hip/hip_runtime.h>
#include <hip/hip_bf16.h>
#include <math.h>

// ---------------- types / helpers ----------------
typedef __attribute__((ext_vector_type(8))) short short8;   // 8 x bf16 (4 VGPR)
typedef __attribute__((ext_vector_type(4))) float f32x4;

#define DMODEL 768
#define THREE_D 2304
#define FFDIM 3072
#define NSEQ 1024
#define NHEAD 12
#define HEADD 64
#define MROWS 4096   // B*N = 4*1024

__device__ __forceinline__ ushort f2bf(float f) {
  union { float f; unsigned u; } c; c.f = f;
  unsigned u = c.u;
  unsigned r = (u + 0x7fffu + ((u >> 16) & 1u)) >> 16;   // RNE
  return (ushort)r;
}

__device__ __forceinline__ unsigned pack2bf(float a, float b) {
  union { __hip_bfloat162 h; unsigned u; } c;
  c.h = __float22bfloat162_rn(make_float2(a, b));   // v_cvt_pk_bf16_f32
  return c.u;
}

// async global->LDS, 16B per lane. LDS dest must be wave-uniform base;
// lane l lands at base + l*16.
__device__ __forceinline__ void load_lds16(const ushort* g, const ushort* l) {
  __builtin_amdgcn_global_load_lds(
      (const __attribute__((address_space(1))) unsigned int*)g,
      (__attribute__((address_space(3))) unsigned int*)l, 16, 0, 0);
}

// ---------------- LayerNorm: fp32 in -> bf16 out ----------------
__global__ __launch_bounds__(256) void ln_kernel(const float* __restrict__ x,
    const float* __restrict__ g, const float* __restrict__ be,
    ushort* __restrict__ out) {
  int row = blockIdx.x;
  const float* xr = x + (size_t)row * DMODEL;
  int tid = threadIdx.x;
  float v0 = xr[tid], v1 = xr[tid + 256], v2 = xr[tid + 512];
  __shared__ float red1[4], red2[4];
  float s = v0 + v1 + v2;
  #pragma unroll
  for (int off = 32; off; off >>= 1) s += __shfl_xor(s, off);
  if ((tid & 63) == 0) red1[tid >> 6] = s;
  __syncthreads();
  float mean = (red1[0] + red1[1] + red1[2] + red1[3]) * (1.0f / 768.0f);
  float d0 = v0 - mean, d1 = v1 - mean, d2 = v2 - mean;
  float q = d0 * d0 + d1 * d1 + d2 * d2;
  #pragma unroll
  for (int off = 32; off; off >>= 1) q += __shfl_xor(q, off);
  if ((tid & 63) == 0) red2[tid >> 6] = q;
  __syncthreads();
  float var = (red2[0] + red2[1] + red2[2] + red2[3]) * (1.0f / 768.0f);
  float rs = rsqrtf(var + 1e-5f);
  size_t base = (size_t)row * DMODEL;
  out[base + tid]       = f2bf(d0 * rs * g[tid]       + be[tid]);
  out[base + tid + 256] = f2bf(d1 * rs * g[tid + 256] + be[tid + 256]);
  out[base + tid + 512] = f2bf(d2 * rs * g[tid + 512] + be[tid + 512]);
}

// ---------------- weight transpose-convert: W[K][N] f32 -> Wt[N][K] bf16 ----
__global__ void wt_kernel(const float* __restrict__ W, ushort* __restrict__ Wt,
                          int K, int N) {
  __shared__ float t[32][33];
  int n0 = blockIdx.x * 32, k0 = blockIdx.y * 32;
  int tx = threadIdx.x, ty = threadIdx.y;
  #pragma unroll
  for (int r = 0; r < 4; r++)
    t[ty + r * 8][tx] = W[(size_t)(k0 + ty + r * 8) * N + n0 + tx];
  __syncthreads();
  #pragma unroll
  for (int r = 0; r < 4; r++)
    Wt[(size_t)(n0 + ty + r * 8) * K + k0 + tx] = f2bf(t[tx][ty + r * 8]);
}

// ---------------- V transpose: qkv(V part) -> Vt[b][h][d][perm(n)] bf16 ----
// Key permutation within each 64-key tile: k' = (k&15)*4 + ((k>>4)&3).
// PV contracts over keys; P columns use the same permutation -> invariant.
__global__ void vt_kernel(const ushort* __restrict__ qkv, ushort* __restrict__ Vt) {
  __shared__ ushort t[32][33];
  int n0 = blockIdx.x * 32, d0 = blockIdx.y * 32, bh = blockIdx.z;
  int b = bh / NHEAD, hh = bh % NHEAD;
  int tx = threadIdx.x, ty = threadIdx.y;
  #pragma unroll
  for (int r = 0; r < 4; r++)
    t[ty + r * 8][tx] = qkv[(size_t)(b * NSEQ + n0 + ty + r * 8) * THREE_D +
                            2 * DMODEL + hh * HEADD + d0 + tx];
  __syncthreads();
  #pragma unroll
  for (int r = 0; r < 4; r++) {
    int n = n0 + tx;
    int np = (n & ~63) | (((n & 15) << 2) | ((n >> 4) & 3));
    Vt[((size_t)bh * HEADD + d0 + ty + r * 8) * NSEQ + np] = t[tx][ty + r * 8];
  }
}

// ---------------- GEMM: C[M][N] = A[M][K](bf16) @ Wt[N][K]^T(bf16) + bias ---
// T3-min 2-phase: double-buffered LDS, ds_read-first / stage-next-tile /
// MFMA / ONE barrier per K-step. Loads fly during compute; the vmcnt(0)
// drain at the barrier hits loads that are already ~done.
// MODE 0: out bf16 = acc + bias
// MODE 1: out f32  = acc + bias + resid
// MODE 2: out bf16 = gelu_exact(acc + bias)
template <int BM, int BN, int MODE>
__global__ __launch_bounds__(256) void gemm_kernel(
    const ushort* __restrict__ A, const ushort* __restrict__ Bt,
    const float* __restrict__ bias, const float* __restrict__ resid,
    void* __restrict__ Cout, int gx, int Ntot, int K) {
  __shared__ ushort Alds[2][BM][64];
  __shared__ ushort Blds[2][BN][64];
  constexpr int WM = BM / 2, WN = BN / 2;   // 2x2 waves
  constexpr int FM = WM / 16, FN = WN / 16;
  int tid = threadIdx.x, lane = tid & 63, wave = tid >> 6;
  int wm = wave >> 1, wn = wave & 1;
  // XCD-chunked swizzle (grid always divisible by 8)
  int nwg = gridDim.x;
  int o = blockIdx.x;
  int wg = (o & 7) * (nwg >> 3) + (o >> 3);
  int bx = wg % gx, by = wg / gx;
  int m0 = by * BM, n0 = bx * BN;
  f32x4 acc[FM][FN] = {};

  auto STAGE = [&](int buf, int k0) {
    #pragma unroll
    for (int i = 0; i < BM / 32; i++) {     // A tile: BM*64 elems, 16B/lane
      int c0 = i * 256 + wave * 64;         // wave-uniform chunk base
      int c = c0 + lane, r = c >> 3;
      int kk = ((c ^ r) & 7) * 8;           // pre-swizzled source col
      load_lds16(&A[(size_t)(m0 + r) * K + k0 + kk],
                 (const ushort*)Alds[buf] + c0 * 8);
    }
    #pragma unroll
    for (int i = 0; i < BN / 32; i++) {
      int c0 = i * 256 + wave * 64;
      int c = c0 + lane, r = c >> 3;
      int kk = ((c ^ r) & 7) * 8;
      load_lds16(&Bt[(size_t)(n0 + r) * K + k0 + kk],
                 (const ushort*)Blds[buf] + c0 * 8);
    }
  };

  STAGE(0, 0);
  __syncthreads();
  int nt = K >> 6;
  for (int t = 0; t < nt; t++) {
    int cur = t & 1;
    // ---- ds_read all fragments for this K-step (reads BEFORE stage) ----
    short8 af[2][FM], bfr[2][FN];
    #pragma unroll
    for (int ks = 0; ks < 2; ks++) {
      int ko = ks * 32 + (lane >> 4) * 8;
      #pragma unroll
      for (int mi = 0; mi < FM; mi++) {
        int R = wm * WM + mi * 16 + (lane & 15);
        af[ks][mi] = *(const short8*)&Alds[cur][R][ko ^ ((R & 7) * 8)];
      }
      #pragma unroll
      for (int ni = 0; ni < FN; ni++) {
        int R = wn * WN + ni * 16 + (lane & 15);
        bfr[ks][ni] = *(const short8*)&Blds[cur][R][ko ^ ((R & 7) * 8)];
      }
    }
    // ---- issue next tile's loads into the other buffer ----
    if (t + 1 < nt) STAGE(cur ^ 1, (t + 1) * 64);
    // ---- MFMA (waits lgkm only; vmem loads fly underneath) ----
    #pragma unroll
    for (int ks = 0; ks < 2; ks++)
      #pragma unroll
      for (int mi = 0; mi < FM; mi++)
        #pragma unroll
        for (int ni = 0; ni < FN; ni++)
          acc[mi][ni] = __builtin_amdgcn_mfma_f32_16x16x32_bf16(
              af[ks][mi], bfr[ks][ni], acc[mi][ni], 0, 0, 0);
    __syncthreads();   // drains vmcnt(0)+lgkm; loads had whole MFMA phase
  }
  // epilogue: C row = (lane>>4)*4+j within 16, col = lane&15
  int rbase = m0 + wm * WM, cbase = n0 + wn * WN;
  #pragma unroll
  for (int ni = 0; ni < FN; ni++) {
    int col = cbase + ni * 16 + (lane & 15);
    float bv = bias[col];
    #pragma unroll
    for (int mi = 0; mi < FM; mi++) {
      int row0 = rbase + mi * 16 + (lane >> 4) * 4;
      #pragma unroll
      for (int j = 0; j < 4; j++) {
        float v = acc[mi][ni][j] + bv;
        size_t idx = (size_t)(row0 + j) * Ntot + col;
        if (MODE == 0) {
          ((ushort*)Cout)[idx] = f2bf(v);
        } else if (MODE == 1) {
          ((float*)Cout)[idx] = v + resid[idx];
        } else {
          float gv = 0.5f * v * (1.0f + erff(v * 0.70710678118654752f));
          ((ushort*)Cout)[idx] = f2bf(gv);
        }
      }
    }
  }
}

// ---------------- flash attention ----------------
// grid: (16 qtiles, 48 b*h), 256 thr = 4 waves x 16 q-rows, KV tiles of 64.
// exp2-domain softmax, MFMA-ones row-sum, packed P writes (key-permuted V),
// double-buffered K/V with reg-staged issue-early/write-late, defer-max.
__global__ __launch_bounds__(256) void attn_kernel(
    const ushort* __restrict__ qkv, const ushort* __restrict__ Vt,
    ushort* __restrict__ o) {
  __shared__ ushort Klds[2][64][72];
  __shared__ ushort Vlds[2][64][72];
  __shared__ ushort Plds[4][16][72];
  const float CL2 = 0.18033688011112042f;   // 0.125 * log2(e)
  int tid = threadIdx.x, lane = tid & 63, wave = tid >> 6;
  int qt = blockIdx.x, bh = blockIdx.y;
  int b = bh / NHEAD, hh = bh % NHEAD;
  int q0 = qt * 64;
  int rsel = lane & 15, quad = lane >> 4;

  short8 qf[2];
  {
    int qrow = q0 + wave * 16 + rsel;
    const ushort* qp = qkv + (size_t)(b * NSEQ + qrow) * THREE_D + hh * HEADD + quad * 8;
    qf[0] = *(const short8*)qp;
    qf[1] = *(const short8*)(qp + 32);
  }
  short8 onesf;
  #pragma unroll
  for (int i = 0; i < 8; i++) onesf[i] = (short)0x3F80;   // bf16 1.0

  // staging geometry: 512 chunks of 8 elems over 2 per-lane loads
  int r0 = tid >> 3, d0 = (tid & 7) * 8;
  int c1 = tid + 256, r1 = c1 >> 3, d1 = (c1 & 7) * 8;
  const ushort* Kg = qkv + (size_t)b * NSEQ * THREE_D + DMODEL + hh * HEADD;
  const ushort* Vg = Vt + (size_t)bh * HEADD * NSEQ;
  int4 kr0, kr1, vr0, vr1;
  auto LD = [&](int kv0) {
    kr0 = *(const int4*)&Kg[(size_t)(kv0 + r0) * THREE_D + d0];
    kr1 = *(const int4*)&Kg[(size_t)(kv0 + r1) * THREE_D + d1];
    vr0 = *(const int4*)&Vg[(size_t)r0 * NSEQ + kv0 + d0];
    vr1 = *(const int4*)&Vg[(size_t)r1 * NSEQ + kv0 + d1];
  };
  auto ST = [&](int bf) {
    *(int4*)&Klds[bf][r0][d0] = kr0;
    *(int4*)&Klds[bf][r1][d1] = kr1;
    *(int4*)&Vlds[bf][r0][d0] = vr0;
    *(int4*)&Vlds[bf][r1][d1] = vr1;
  };

  f32x4 oacc[4] = {};
  f32x4 osum = {};
  float m2[4];
  #pragma unroll
  for (int i = 0; i < 4; i++) m2[i] = -INFINITY;

  LD(0); ST(0); __syncthreads();

  for (int t = 0; t < 16; t++) {
    int bf = t & 1;
    if (t < 15) LD((t + 1) * 64);           // issue next-tile loads early
    // ---- S = Q K^T (raw, scale folded into exp2 constant) ----
    f32x4 sfr[4] = {};
    __builtin_amdgcn_s_setprio(1);
    #pragma unroll
    for (int ks = 0; ks < 2; ks++) {
      int ko = ks * 32 + quad * 8;
      #pragma unroll
      for (int nt = 0; nt < 4; nt++) {
        short8 kf = *(const short8*)&Klds[bf][nt * 16 + rsel][ko];
        sfr[nt] = __builtin_amdgcn_mfma_f32_16x16x32_bf16(qf[ks], kf, sfr[nt], 0, 0, 0);
      }
    }
    __builtin_amdgcn_s_setprio(0);
    // ---- online softmax (exp2 domain) ----
    float m2c[4];
    bool ok = true;
    #pragma unroll
    for (int i = 0; i < 4; i++) {
      float mx = fmaxf(fmaxf(sfr[0][i], sfr[1][i]), fmaxf(sfr[2][i], sfr[3][i]));
      #pragma unroll
      for (int off = 1; off < 16; off <<= 1) mx = fmaxf(mx, __shfl_xor(mx, off));
      m2c[i] = mx * CL2;
      ok = ok && (m2c[i] <= m2[i] + 8.0f);
    }
    if (!__all(ok)) {                        // rescale path
      #pragma unroll
      for (int i = 0; i < 4; i++) {
        float mn = fmaxf(m2[i], m2c[i]);
        float al = exp2f(m2[i] - mn);
        m2[i] = mn;
        #pragma unroll
        for (int nt = 0; nt < 4; nt++) oacc[nt][i] *= al;
        osum[i] *= al;
      }
    }
    #pragma unroll
    for (int i = 0; i < 4; i++) {
      float p0 = exp2f(fmaf(sfr[0][i], CL2, -m2[i]));
      float p1 = exp2f(fmaf(sfr[1][i], CL2, -m2[i]));
      float p2 = exp2f(fmaf(sfr[2][i], CL2, -m2[i]));
      float p3 = exp2f(fmaf(sfr[3][i], CL2, -m2[i]));
      // columns k' = rsel*4 + nt  (key-permuted; V uses same permutation)
      uint2 pw = make_uint2(pack2bf(p0, p1), pack2bf(p2, p3));
      *(uint2*)&Plds[wave][quad * 4 + i][rsel * 4] = pw;
    }
    // ---- O += P @ V ; row-sum via ones-column MFMA ----
    __builtin_amdgcn_s_setprio(1);
    #pragma unroll
    for (int ks = 0; ks < 2; ks++) {
      int ko = ks * 32 + quad * 8;
      short8 pf = *(const short8*)&Plds[wave][rsel][ko];
      #pragma unroll
      for (int nt = 0; nt < 4; nt++) {
        short8 vf = *(const short8*)&Vlds[bf][nt * 16 + rsel][ko];
        oacc[nt] = __builtin_amdgcn_mfma_f32_16x16x32_bf16(pf, vf, oacc[nt], 0, 0, 0);
      }
      osum = __builtin_amdgcn_mfma_f32_16x16x32_bf16(pf, onesf, osum, 0, 0, 0);
    }
    __builtin_amdgcn_s_setprio(0);
    if (t < 15) ST(bf ^ 1);                  // write-late into other buffer
    __syncthreads();
  }
  // ---- epilogue ----
  float rin[4];
  #pragma unroll
  for (int i = 0; i < 4; i++) rin[i] = __builtin_amdgcn_rcpf(osum[i]);
  #pragma unroll
  for (int nt = 0; nt < 4; nt++)
    #pragma unroll
    for (int i = 0; i < 4; i++) {
      int qrow = q0 + wave * 16 + quad * 4 + i;
      int col = hh * HEADD + nt * 16 + rsel;
      o[(size_t)(b * NSEQ + qrow) * DMODEL + col] = f2bf(oacc[nt][i] * rin[i]);
    }
}

// ---------------- launch ----------------
extern "C" void kernel_launch(void* const* d_in, const int* in_sizes, int n_in,
                              void* d_out, int out_size, void* d_ws, size_t ws_size,
                              hipStream_t stream) {
  const float* x      = (const float*)d_in[0];
  const float* w_qkv  = (const float*)d_in[1];
  const float* b_qkv  = (const float*)d_in[2];
  const float* w_proj = (const float*)d_in[3];
  const float* b_proj = (const float*)d_in[4];
  const float* w1     = (const float*)d_in[5];
  const float* b1     = (const float*)d_in[6];
  const float* w2     = (const float*)d_in[7];
  const float* b2     = (const float*)d_in[8];
  const float* g1     = (const float*)d_in[9];
  const float* be1    = (const float*)d_in[10];
  const float* g2     = (const float*)d_in[11];
  const float* be2    = (const float*)d_in[12];
  float* out = (float*)d_out;

  char* ws = (char*)d_ws;
  ushort* Wqkv_t  = (ushort*)(ws + 0);           // 2304*768*2  = 3538944
  ushort* Wproj_t = (ushort*)(ws + 3538944);     // 768*768*2   = 1179648
  ushort* W1_t    = (ushort*)(ws + 4718592);     // 3072*768*2  = 4718592
  ushort* W2_t    = (ushort*)(ws + 9437184);     // 768*3072*2  = 4718592
  ushort* hbuf    = (ushort*)(ws + 14155776);    // 4096*768*2  = 6291456 (h, then h2)
  ushort* qkv     = (ushort*)(ws + 20447232);    // max(qkv 18.9MB, ff1 25.2MB)
  ushort* ff1     = qkv;
  ushort* VtB     = (ushort*)(ws + 45613056);    // 4096*768*2
  ushort* obuf    = (ushort*)(ws + 51904512);    // 4096*768*2
  float*  x2      = (float*)(ws + 58195968);     // 4096*768*4 -> end 70778880

  dim3 tb(32, 8);
  wt_kernel<<<dim3(THREE_D / 32, DMODEL / 32), tb, 0, stream>>>(w_qkv, Wqkv_t, DMODEL, THREE_D);
  wt_kernel<<<dim3(DMODEL / 32, DMODEL / 32), tb, 0, stream>>>(w_proj, Wproj_t, DMODEL, DMODEL);
  wt_kernel<<<dim3(FFDIM / 32, DMODEL / 32), tb, 0, stream>>>(w1, W1_t, DMODEL, FFDIM);
  wt_kernel<<<dim3(DMODEL / 32, FFDIM / 32), tb, 0, stream>>>(w2, W2_t, FFDIM, DMODEL);

  ln_kernel<<<MROWS, 256, 0, stream>>>(x, g1, be1, hbuf);

  // QKV: M=4096 N=2304 K=768, 128x128 -> 18*32=576 blocks
  gemm_kernel<128, 128, 0><<<576, 256, 0, stream>>>(
      hbuf, Wqkv_t, b_qkv, nullptr, qkv, THREE_D / 128, THREE_D, DMODEL);

  vt_kernel<<<dim3(NSEQ / 32, HEADD / 32, 4 * NHEAD), tb, 0, stream>>>(qkv, VtB);

  attn_kernel<<<dim3(NSEQ / 64, 4 * NHEAD), 256, 0, stream>>>(qkv, VtB, obuf);

  // proj: M=4096 N=768 K=768, 128x64 -> 12*32=384 blocks
  gemm_kernel<128, 64, 1><<<384, 256, 0, stream>>>(
      obuf, Wproj_t, b_proj, x, x2, DMODEL / 64, DMODEL, DMODEL);

  ln_kernel<<<MROWS, 256, 0, stream>>>(x2, g2, be2, hbuf);

  // FF1: M=4096 N=3072 K=768, 128x128 -> 24*32=768 blocks
  gemm_kernel<128, 128, 2><<<768, 256, 0, stream>>>(
      hbuf, W1_t, b1, nullptr, ff1, FFDIM / 128, FFDIM, DMODEL);

  // FF2: M=4096 N=768 K=3072, 128x64 -> 384 blocks
  gemm_kernel<128, 64, 1><<<384, 256, 0, stream>>>(
      ff1, W2_t, b2, x2, out, DMODEL / 64, DMODEL, FFDIM);

  (void)in_sizes; (void)n_in; (void)out_size; (void)ws_size;
}